// Round 12
// baseline (463.803 us; speedup 1.0000x reference)
//
#include <hip/hip_runtime.h>
#include <cstddef>

typedef unsigned short ushort_t;
typedef unsigned uv4 __attribute__((ext_vector_type(4)));
typedef unsigned uv2 __attribute__((ext_vector_type(2)));
typedef float f32x4 __attribute__((ext_vector_type(4)));

// ---------------- problem constants ----------------
constexpr int Bfull = 512;
constexpr int F = 4, O = 10;

// per-image byte sizes (all 16B-aligned)
constexpr size_t TB_B  = (size_t)136 * 136 * 4 * 2;   // 147,968
constexpr size_t P1_B  = (size_t)35 * 35 * 32 * 2;    // 78,400 (each of h,l)
constexpr size_t P2_B  = (size_t)17 * 18 * 64 * 2;    // 39,168 (each of h,l)
constexpr size_t FEAT_B = (size_t)Bfull * 128 * 4;    // 262,144
constexpr size_t W1P_ELEMS = (size_t)7 * 4 * 16 * 32;        // 28672 ushort
constexpr size_t W2P_ELEMS = (size_t)25 * 2 * 64 * 32;       // 102400 ushort
constexpr size_t W3P_ELEMS = (size_t)9 * 2 * 2 * 128 * 32;   // 147456 ushort

__device__ __forceinline__ ushort_t f2bf_rne(float x) {
    unsigned u = __builtin_bit_cast(unsigned, x);
    unsigned r = (u + 0x7FFFu + ((u >> 16) & 1u)) >> 16;
    return (ushort_t)r;
}
__device__ __forceinline__ float bf2f(ushort_t b) {
    return __builtin_bit_cast(float, (unsigned)b << 16);
}

#define MFMA16(acc, a, b) \
    asm("v_mfma_f32_16x16x32_bf16 %0, %1, %2, %0" : "+v"(acc) : "v"(a), "v"(b))

// ---------------- rasterize -> padded bf16 [b][136r][136c][4ic] ----------------
__global__ __launch_bounds__(256) void rasterize_bf_k(const int* __restrict__ x,
                                                      ushort_t* __restrict__ tb, int b0) {
    int b_l = blockIdx.x;
    int rg  = blockIdx.y;             // row-group 0..7
    int b = b0 + b_l;
    __shared__ int pts[F][O][2];
    __shared__ int prm[F][24];
    int tid = threadIdx.x;
    if (tid < F * O * 2)
        ((int*)pts)[tid] = x[(size_t)b * F * O * 2 + tid];
    __syncthreads();
    if (tid < F) {
        int f = tid;
        int dX = 64 + pts[f][O - 1][0];
        int dY = 64 - pts[f][O - 1][1];
        prm[f][0] = dX; prm[f][1] = dY;
        prm[f][2] = dX >= 64 ? 64 : dX + 1; prm[f][3] = dX >= 64 ? dX - 1 : 64;
        prm[f][4] = dY >= 64 ? 64 : dY + 1; prm[f][5] = dY >= 64 ? dY - 1 : 64;
        for (int k = 0; k < O - 1; ++k) {
            prm[f][6 + k]  = (pts[f][k][0] + 64) % 127;
            prm[f][15 + k] = (64 - pts[f][k][1]) % 127;
        }
    }
    __syncthreads();
    ushort_t* outp = tb + (size_t)b_l * 136 * 136 * 4;
    int r0 = rg * 17;
    for (int i = tid; i < 17 * 136; i += 256) {
        int r = r0 + i / 136, c = i % 136;
        int y = r - 3, xx = c - 3;
        unsigned pack0 = 0, pack1 = 0;
        if (y >= 0 && y < 128 && xx >= 0 && xx < 128) {
            bool ctr9 = (y >= 63 && y <= 65 && xx >= 63 && xx <= 65);
            bool ctr1 = (y == 64 && xx == 64);
            #pragma unroll
            for (int f = 0; f < 4; ++f) {
                unsigned bf;
                if (ctr1) bf = 0x3F80u;
                else if (ctr9) bf = 0x3F00u;
                else {
                    int dX = prm[f][0];
                    bool mX = (xx >= prm[f][2]) && (xx <= prm[f][3]);
                    bool mY = (y >= prm[f][4]) && (y <= prm[f][5]);
                    bf = ((mX && y == 64) || (mY && xx == dX)) ? 0xBF80u : 0u;
                }
                if (f & 1) { if (f >> 1) pack1 |= bf << 16; else pack0 |= bf << 16; }
                else       { if (f >> 1) pack1 |= bf;       else pack0 |= bf; }
            }
        }
        uv2 pk; pk.x = pack0; pk.y = pack1;
        *(uv2*)(outp + ((size_t)r * 136 + c) * 4) = pk;
    }
    __syncthreads();
    if (tid < 4) {
        int f = tid;
        int r1 = r0 + 17;
        for (int k = 0; k < O - 1; ++k) {
            int a = prm[f][6 + k] + 3, bb = prm[f][15 + k] + 3;
            #pragma unroll
            for (int dy = -1; dy <= 1; ++dy) {
                int rr = bb + dy;
                if (rr >= r0 && rr < r1) {
                    ushort_t* rowp = outp + ((size_t)rr * 136 + a - 1) * 4 + f;
                    rowp[0] = 0x3F00u; rowp[4] = 0x3F00u; rowp[8] = 0x3F00u;
                }
            }
            if (bb >= r0 && bb < r1) outp[((size_t)bb * 136 + a) * 4 + f] = 0x3F80u;
        }
    }
}

// ---------------- prep_w1 ----------------
__global__ __launch_bounds__(256) void prep_w1_k(const float* __restrict__ w1,
                                                 ushort_t* __restrict__ w1p) {
    int idx = blockIdx.x * 256 + threadIdx.x;
    if (idx >= (int)W1P_ELEMS) return;
    int k = idx & 31, lr = (idx >> 5) & 15, slot = (idx >> 9) & 3, ky = idx >> 11;
    int hl = slot & 1, m = slot >> 1;
    int kx = k >> 2, ic = k & 3;
    int oc = m * 16 + lr;
    float w = (kx < 7) ? w1[((oc * 4 + ic) * 7 + ky) * 7 + kx] : 0.f;
    ushort_t h = f2bf_rne(w);
    w1p[idx] = hl ? f2bf_rne(w - bf2f(h)) : h;
}

// ---------------- conv1 + pool1 fused (packed-LDS x-pool) ----------------
// grid (NB, 4); wave w computes conv rows yt*16+4w..+4 (5 rows, 1 redundant),
// row-pools into registers, writes packed bf16 h|l to LDS; after barrier a
// simple indexed phase reconstructs h+l, x-pools cols 2px..2px+2, stores p1.
__global__ __launch_bounds__(256) void conv1pool_k(const ushort_t* __restrict__ tb,
                                                   const ushort_t* __restrict__ w1p,
                                                   const float* __restrict__ b1,
                                                   ushort_t* __restrict__ p1h,
                                                   ushort_t* __restrict__ p1l) {
    __shared__ unsigned sP[8 * 64 * 33];   // [prow][col][ch] packed h|l<<16; 33,792 B
    int b_l = blockIdx.x;
    int yt  = blockIdx.y;
    int wave = threadIdx.x >> 6, lane = threadIdx.x & 63;
    int lr = lane & 15, lq = lane >> 4;
    const ushort_t* tbb = tb + (size_t)b_l * 136 * 136 * 4;
    int aoff = lr * 32 + lq * 8;
    float bias[2][4];
    #pragma unroll
    for (int m = 0; m < 2; ++m)
        #pragma unroll
        for (int j = 0; j < 4; ++j)
            bias[m][j] = b1[m * 16 + lq * 4 + j];
    int base = yt * 16 + wave * 4;

    f32x4 pacc[2][2][4];   // [pr][m][xt]; relu >= 0 so 0 is max-identity
    #pragma unroll
    for (int p = 0; p < 2; ++p)
        #pragma unroll
        for (int m = 0; m < 2; ++m)
            #pragma unroll
            for (int xt = 0; xt < 4; ++xt)
                pacc[p][m][xt] = (f32x4)0.f;

    #pragma unroll 1
    for (int rr = 0; rr < 5; ++rr) {
        int oy = base + rr; oy = oy > 63 ? 63 : oy;
        f32x4 acc[2][4];
        #pragma unroll
        for (int m = 0; m < 2; ++m)
            #pragma unroll
            for (int xt = 0; xt < 4; ++xt)
                acc[m][xt] = (f32x4)0.f;
        #pragma unroll
        for (int ky = 0; ky < 7; ++ky) {
            const ushort_t* wb = w1p + (size_t)ky * 2048;
            uv4 ah0 = *(const uv4*)(wb + aoff);
            uv4 al0 = *(const uv4*)(wb + 512 + aoff);
            uv4 ah1 = *(const uv4*)(wb + 1024 + aoff);
            uv4 al1 = *(const uv4*)(wb + 1536 + aoff);
            const ushort_t* rb = tbb + (size_t)(2 * oy + ky) * (136 * 4);
            #pragma unroll
            for (int xt = 0; xt < 4; ++xt) {
                uv4 bv = *(const uv4*)(rb + (size_t)(2 * (xt * 16 + lr) + 2 * lq) * 4);
                MFMA16(acc[0][xt], ah0, bv);
                MFMA16(acc[1][xt], ah1, bv);
                MFMA16(acc[0][xt], al0, bv);
                MFMA16(acc[1][xt], al1, bv);
            }
        }
        asm volatile("s_nop 7\n\ts_nop 7");
        #pragma unroll
        for (int m = 0; m < 2; ++m)
            #pragma unroll
            for (int xt = 0; xt < 4; ++xt)
                #pragma unroll
                for (int j = 0; j < 4; ++j) {
                    float v = fmaxf(acc[m][xt][j] + bias[m][j], 0.f);
                    if (rr <= 2) pacc[0][m][xt][j] = fmaxf(pacc[0][m][xt][j], v);
                    if (rr >= 2) pacc[1][m][xt][j] = fmaxf(pacc[1][m][xt][j], v);
                }
    }

    // write row-pooled values (packed h|l) to LDS: prow = 2*wave + pr
    int prow0 = 2 * wave;
    #pragma unroll
    for (int pr = 0; pr < 2; ++pr)
        #pragma unroll
        for (int m = 0; m < 2; ++m)
            #pragma unroll
            for (int xt = 0; xt < 4; ++xt) {
                int col = xt * 16 + lr;
                unsigned* dst = &sP[((prow0 + pr) * 64 + col) * 33 + m * 16 + lq * 4];
                #pragma unroll
                for (int j = 0; j < 4; ++j) {
                    float v = pacc[pr][m][xt][j];
                    ushort_t h = f2bf_rne(v);
                    ushort_t l = f2bf_rne(v - bf2f(h));
                    dst[j] = (unsigned)h | ((unsigned)l << 16);
                }
            }
    __syncthreads();

    // x-pool on h+l reconstructions + hi/lo split + store interior p1 cells
    for (int i = threadIdx.x; i < 8 * 31 * 32; i += 256) {
        int ch = i & 31; int t = i >> 5;
        int px = t % 31; int r = t / 31;
        int py = yt * 8 + r;
        if (py > 30) continue;
        const unsigned* s = &sP[((size_t)r * 64 + 2 * px) * 33 + ch];
        float v = 0.f;
        #pragma unroll
        for (int c = 0; c < 3; ++c) {
            unsigned u = s[33 * c];
            v = fmaxf(v, bf2f((ushort_t)(u & 0xFFFFu)) + bf2f((ushort_t)(u >> 16)));
        }
        ushort_t h = f2bf_rne(v);
        size_t addr = (((size_t)b_l * 35 + py + 2) * 35 + px + 2) * 32 + ch;
        p1h[addr] = h;
        p1l[addr] = f2bf_rne(v - bf2f(h));
    }
}

// ---------------- prep_w2 ----------------
__global__ __launch_bounds__(256) void prep_w2_k(const float* __restrict__ w2,
                                                 ushort_t* __restrict__ w2p) {
    int idx = blockIdx.x * 256 + threadIdx.x;
    if (idx >= 25 * 64 * 32) return;
    int ic = idx & 31, oc = (idx >> 5) & 63, kk = idx >> 11;
    float w = w2[(size_t)(oc * 32 + ic) * 25 + kk];
    ushort_t h = f2bf_rne(w);
    w2p[(size_t)kk * 4096 + (idx & 2047)] = h;
    w2p[(size_t)kk * 4096 + 2048 + (idx & 2047)] = f2bf_rne(w - bf2f(h));
}

// ---------------- conv2 MFMA + LDS-staged B (pad-zeroing) + fused bias/relu/pool2 ----------------
__global__ __launch_bounds__(256) void conv2_mfma_k(const ushort_t* __restrict__ p1h,
                                                    const ushort_t* __restrict__ p1l,
                                                    const ushort_t* __restrict__ w2p,
                                                    const float* __restrict__ b2,
                                                    ushort_t* __restrict__ p2h,
                                                    ushort_t* __restrict__ p2l) {
    __shared__ ushort_t sB[2][13440];   // [plane][r<12][pc<35][k<32], swizzled k-chunk
    int b_l = blockIdx.x;
    int yt  = blockIdx.y;
    int y0 = yt * 8;
    int nrows = (35 - y0) < 12 ? (35 - y0) : 12;   // 12,12,12,11
    int tid = threadIdx.x;

    {
        int nchunks = nrows * 35 * 4;
        const ushort_t* src0 = p1h + (size_t)b_l * 35 * 1120 + (size_t)y0 * 1120;
        const ushort_t* src1 = p1l + (size_t)b_l * 35 * 1120 + (size_t)y0 * 1120;
        for (int c = tid; c < 2 * nchunks; c += 256) {
            int p = c >= nchunks;
            int cc = p ? c - nchunks : c;
            int lqi = cc & 3;
            int pc = (cc >> 2) % 35;
            int r = cc / 140;
            int pr_g = y0 + r;
            bool inb = (pr_g >= 2 && pr_g <= 32 && pc >= 2 && pc <= 32);
            const ushort_t* s = p ? src1 : src0;
            uv4 v = *(const uv4*)(s + (size_t)r * 1120 + pc * 32 + lqi * 8);
            if (!inb) v = (uv4)0u;     // p1 pads are never written: zero-fill here
            int swz = lqi ^ ((pc >> 1) & 3);
            *(uv4*)(&sB[p][(r * 35 + pc) * 32 + swz * 8]) = v;
        }
    }
    __syncthreads();

    int wave = threadIdx.x >> 6;
    int lane = threadIdx.x & 63;
    int wm = wave & 1, wy = wave >> 1;
    int oc0 = wm * 32;
    int lr = lane & 15, lq = lane >> 4;
    int rclip = 34 - y0;

    f32x4 acc[4][2][2];
    #pragma unroll
    for (int y = 0; y < 4; ++y)
        #pragma unroll
        for (int m = 0; m < 2; ++m)
            #pragma unroll
            for (int n = 0; n < 2; ++n)
                acc[y][m][n] = (f32x4)0.f;

    int aoff = (oc0 + lr) * 32 + lq * 8;

    #pragma unroll 1
    for (int kk = 0; kk < 25; ++kk) {
        int ky = kk / 5, kx = kk % 5;
        const ushort_t* wb = w2p + (size_t)kk * 4096;
        uv4 ah0 = *(const uv4*)(wb + aoff);
        uv4 ah1 = *(const uv4*)(wb + aoff + 512);
        uv4 al0 = *(const uv4*)(wb + 2048 + aoff);
        uv4 al1 = *(const uv4*)(wb + 2048 + aoff + 512);
        int pcc[2];
        #pragma unroll
        for (int xt = 0; xt < 2; ++xt) {
            int pc = xt * 16 + lr + kx; pc = pc > 34 ? 34 : pc;
            pcc[xt] = pc * 32 + (lq ^ ((pc >> 1) & 3)) * 8;
        }
        #pragma unroll
        for (int y = 0; y < 4; ++y) {
            int r = wy * 4 + y + ky; r = r > rclip ? rclip : r;
            int rbase = r * 1120;
            #pragma unroll
            for (int xt = 0; xt < 2; ++xt) {
                int off = rbase + pcc[xt];
                uv4 bh = *(const uv4*)(&sB[0][off]);
                uv4 bl = *(const uv4*)(&sB[1][off]);
                MFMA16(acc[y][0][xt], ah0, bh);
                MFMA16(acc[y][1][xt], ah1, bh);
                MFMA16(acc[y][0][xt], ah0, bl);
                MFMA16(acc[y][1][xt], ah1, bl);
                MFMA16(acc[y][0][xt], al0, bh);
                MFMA16(acc[y][1][xt], al1, bh);
            }
        }
    }
    asm volatile("s_nop 7\n\ts_nop 7");

    float bias[2][4];
    #pragma unroll
    for (int m = 0; m < 2; ++m)
        #pragma unroll
        for (int j = 0; j < 4; ++j)
            bias[m][j] = b2[oc0 + m * 16 + lq * 4 + j];

    int ybase = y0 + wy * 4;
    #pragma unroll
    for (int yp = 0; yp < 2; ++yp) {
        int yy = ybase + 2 * yp;
        if (yy + 1 > 30) continue;   // wave-uniform
        int py = yy >> 1;
        #pragma unroll
        for (int m = 0; m < 2; ++m)
            #pragma unroll
            for (int xt = 0; xt < 2; ++xt)
                #pragma unroll
                for (int j = 0; j < 4; ++j) {
                    float v = fmaxf(acc[2 * yp][m][xt][j], acc[2 * yp + 1][m][xt][j]);
                    float o = __shfl_xor(v, 1, 64);
                    v = fmaxf(fmaxf(v, o) + bias[m][j], 0.f);
                    int px = xt * 8 + (lr >> 1);
                    if (!(lane & 1) && px < 15) {
                        int oc = oc0 + m * 16 + lq * 4 + j;
                        size_t oo = (((size_t)b_l * 17 + py + 1) * 18 + px + 1) * 64 + oc;
                        ushort_t h = f2bf_rne(v);
                        p2h[oo] = h;
                        p2l[oo] = f2bf_rne(v - bf2f(h));
                    }
                }
    }
}

// ---------------- prep_w3 ----------------
__global__ __launch_bounds__(256) void prep_w3_k(const float* __restrict__ w3,
                                                 ushort_t* __restrict__ w3p) {
    int idx = blockIdx.x * 256 + threadIdx.x;
    if (idx >= (int)W3P_ELEMS) return;
    int kk = idx & 31, oc = (idx >> 5) & 127, hl = (idx >> 12) & 1, ks = (idx >> 13) & 1, kxy = idx >> 14;
    int ky = kxy / 3, kx = kxy % 3;
    int ic = ks * 32 + kk;
    float w = w3[((size_t)(oc * 64 + ic) * 3 + ky) * 3 + kx];
    ushort_t h = f2bf_rne(w);
    w3p[idx] = hl ? f2bf_rne(w - bf2f(h)) : h;
}

// ---------------- conv3 + pool3 + mean, fused -> feat ----------------
// p2 pads are never written in global: staging zero-fills pad cells.
__global__ __launch_bounds__(256) void conv3pool_k(const ushort_t* __restrict__ p2h,
                                                   const ushort_t* __restrict__ p2l,
                                                   const ushort_t* __restrict__ w3p,
                                                   const float* __restrict__ b3,
                                                   float* __restrict__ feat, int b0) {
    __shared__ ushort_t sB[2][19584];   // [plane][rc<306][64], 16B slots swizzled by c&7
    int b_l = blockIdx.x;
    int tid = threadIdx.x;
    {
        const ushort_t* s0 = p2h + (size_t)b_l * 19584;
        const ushort_t* s1 = p2l + (size_t)b_l * 19584;
        for (int ccg = tid; ccg < 4896; ccg += 256) {
            int p = ccg >= 2448;
            int cc = p ? ccg - 2448 : ccg;
            int rc = cc >> 3, slot = cc & 7;
            int r = rc / 18, c = rc % 18;
            bool pad = (r == 0 || r == 16 || c == 0 || c >= 16);
            uv4 v = *(const uv4*)((p ? s1 : s0) + (size_t)cc * 8);
            if (pad) v = (uv4)0u;
            *(uv4*)(&sB[p][rc * 64 + (slot ^ (c & 7)) * 8]) = v;
        }
    }
    __syncthreads();
    int wave = tid >> 6, lane = tid & 63;
    int lr = lane & 15, lq = lane >> 4;
    int oc0 = wave * 32;
    float bias[2][4];
    #pragma unroll
    for (int m = 0; m < 2; ++m)
        #pragma unroll
        for (int j = 0; j < 4; ++j)
            bias[m][j] = b3[oc0 + m * 16 + lq * 4 + j];
    f32x4 fsum[2];
    fsum[0] = (f32x4)0.f; fsum[1] = (f32x4)0.f;

    int cl = lr;
    #pragma unroll 1
    for (int pr = 0; pr < 7; ++pr) {
        f32x4 acc[2][2];
        #pragma unroll
        for (int rr = 0; rr < 2; ++rr) { acc[rr][0] = (f32x4)0.f; acc[rr][1] = (f32x4)0.f; }
        #pragma unroll 1
        for (int ky = 0; ky < 3; ++ky)
            #pragma unroll 1
            for (int kx = 0; kx < 3; ++kx) {
                int c = cl + kx;
                int cs = c & 7;
                #pragma unroll
                for (int ks = 0; ks < 2; ++ks) {
                    const ushort_t* wb = w3p + (size_t)(((ky * 3 + kx) * 2 + ks) * 2) * 4096;
                    uv4 ah0 = *(const uv4*)(wb + (oc0 + lr) * 32 + lq * 8);
                    uv4 ah1 = *(const uv4*)(wb + (oc0 + 16 + lr) * 32 + lq * 8);
                    uv4 al0 = *(const uv4*)(wb + 4096 + (oc0 + lr) * 32 + lq * 8);
                    uv4 al1 = *(const uv4*)(wb + 4096 + (oc0 + 16 + lr) * 32 + lq * 8);
                    int slotk = ((ks << 2) | lq) ^ cs;
                    #pragma unroll
                    for (int rr = 0; rr < 2; ++rr) {
                        int r = 2 * pr + rr + ky;
                        int off = (r * 18 + c) * 64 + slotk * 8;
                        uv4 bh = *(const uv4*)(&sB[0][off]);
                        uv4 bl = *(const uv4*)(&sB[1][off]);
                        MFMA16(acc[rr][0], ah0, bh);
                        MFMA16(acc[rr][1], ah1, bh);
                        MFMA16(acc[rr][0], ah0, bl);
                        MFMA16(acc[rr][1], ah1, bl);
                        MFMA16(acc[rr][0], al0, bh);
                        MFMA16(acc[rr][1], al1, bh);
                    }
                }
            }
        asm volatile("s_nop 7\n\ts_nop 7");
        #pragma unroll
        for (int m = 0; m < 2; ++m)
            #pragma unroll
            for (int j = 0; j < 4; ++j) {
                float v0 = fmaxf(acc[0][m][j] + bias[m][j], 0.f);
                float v1 = fmaxf(acc[1][m][j] + bias[m][j], 0.f);
                float vm = fmaxf(v0, v1);
                float o = __shfl_xor(vm, 1, 64);
                float pooled = fmaxf(vm, o);
                if (lr < 14) fsum[m][j] += pooled;
            }
    }
    #pragma unroll
    for (int m = 0; m < 2; ++m)
        #pragma unroll
        for (int j = 0; j < 4; ++j) {
            float t = fsum[m][j];
            t += __shfl_xor(t, 1, 64);
            t += __shfl_xor(t, 2, 64);
            t += __shfl_xor(t, 4, 64);
            t += __shfl_xor(t, 8, 64);
            if (lr == 0)
                feat[(size_t)(b0 + b_l) * 128 + oc0 + m * 16 + lq * 4 + j] = t * (1.f / 98.f);
        }
}

// ---------------- fc1 (relu) + fc2 ----------------
__global__ __launch_bounds__(128) void fc_k(const float* __restrict__ feat,
                                            const float* __restrict__ fw1,
                                            const float* __restrict__ fb1,
                                            const float* __restrict__ fw2,
                                            const float* __restrict__ fb2,
                                            float* __restrict__ out) {
    __shared__ float sF[128];
    __shared__ float sH[128];
    int b = blockIdx.x, tid = threadIdx.x;
    sF[tid] = feat[(size_t)b * 128 + tid];
    __syncthreads();
    const float4* wrow = (const float4*)(fw1 + (size_t)tid * 128);
    float s = fb1[tid];
    #pragma unroll
    for (int i = 0; i < 32; ++i) {
        float4 w = wrow[i];
        s = fmaf(w.x, sF[4 * i], s);
        s = fmaf(w.y, sF[4 * i + 1], s);
        s = fmaf(w.z, sF[4 * i + 2], s);
        s = fmaf(w.w, sF[4 * i + 3], s);
    }
    sH[tid] = fmaxf(s, 0.f);
    __syncthreads();
    if (tid < 5) {
        const float* w2r = fw2 + (size_t)tid * 128;
        float s2 = fb2[tid];
        for (int i = 0; i < 128; ++i) s2 = fmaf(w2r[i], sH[i], s2);
        out[(size_t)b * 5 + tid] = s2;
    }
}

// ---------------- launch ----------------
extern "C" void kernel_launch(void* const* d_in, const int* in_sizes, int n_in,
                              void* d_out, int out_size, void* d_ws, size_t ws_size,
                              hipStream_t stream) {
    const int*   x   = (const int*)d_in[0];
    const float* w1  = (const float*)d_in[1];
    const float* b1  = (const float*)d_in[2];
    const float* w2  = (const float*)d_in[3];
    const float* b2  = (const float*)d_in[4];
    const float* w3  = (const float*)d_in[5];
    const float* b3  = (const float*)d_in[6];
    const float* fw1 = (const float*)d_in[7];
    const float* fb1 = (const float*)d_in[8];
    const float* fw2 = (const float*)d_in[9];
    const float* fb2 = (const float*)d_in[10];
    float* out = (float*)d_out;

    const size_t per_img = TB_B + 2 * P1_B + 2 * P2_B;   // 383,104 B
    const size_t fixed_b = FEAT_B + (W1P_ELEMS + W2P_ELEMS + W3P_ELEMS) * 2 + 1024;
    int NB = Bfull;
    while (NB > 128 && fixed_b + per_img * (size_t)NB > ws_size) NB >>= 1;

    char* base = (char*)d_ws;
    float* feat = (float*)base;                         base += FEAT_B;
    ushort_t* tb  = (ushort_t*)base;                    base += (size_t)NB * TB_B;
    ushort_t* p1h = (ushort_t*)base;                    base += (size_t)NB * P1_B;
    ushort_t* p1l = (ushort_t*)base;                    base += (size_t)NB * P1_B;
    ushort_t* p2h = (ushort_t*)base;                    base += (size_t)NB * P2_B;
    ushort_t* p2l = (ushort_t*)base;                    base += (size_t)NB * P2_B;
    ushort_t* w1p = (ushort_t*)base;                    base += W1P_ELEMS * 2;
    ushort_t* w2p = (ushort_t*)base;                    base += W2P_ELEMS * 2;
    ushort_t* w3p = (ushort_t*)base;

    prep_w1_k<<<((int)W1P_ELEMS + 255) / 256, 256, 0, stream>>>(w1, w1p);
    prep_w2_k<<<(25 * 64 * 32 + 255) / 256, 256, 0, stream>>>(w2, w2p);
    prep_w3_k<<<((int)W3P_ELEMS + 255) / 256, 256, 0, stream>>>(w3, w3p);

    const int nchunk = Bfull / NB;
    for (int ch = 0; ch < nchunk; ++ch) {
        int b0 = ch * NB;
        rasterize_bf_k<<<dim3(NB, 8), 256, 0, stream>>>(x, tb, b0);
        conv1pool_k<<<dim3(NB, 4), 256, 0, stream>>>(tb, w1p, b1, p1h, p1l);
        conv2_mfma_k<<<dim3(NB, 4), 256, 0, stream>>>(p1h, p1l, w2p, b2, p2h, p2l);
        conv3pool_k<<<NB, 256, 0, stream>>>(p2h, p2l, w3p, b3, feat, b0);
    }
    fc_k<<<Bfull, 128, 0, stream>>>(feat, fw1, fb1, fw2, fb2, out);
}

// Round 13
// 429.203 us; speedup vs baseline: 1.0806x; 1.0806x over previous
//
#include <hip/hip_runtime.h>
#include <cstddef>

typedef unsigned short ushort_t;
typedef unsigned uv4 __attribute__((ext_vector_type(4)));
typedef unsigned uv2 __attribute__((ext_vector_type(2)));
typedef float f32x4 __attribute__((ext_vector_type(4)));

// ---------------- problem constants ----------------
constexpr int Bfull = 512;
constexpr int F = 4, O = 10;

// per-image byte sizes (all 16B-aligned)
constexpr size_t TB_B  = (size_t)136 * 136 * 4 * 2;   // 147,968
constexpr size_t P1_B  = (size_t)35 * 35 * 32 * 2;    // 78,400 (each of h,l)
constexpr size_t P2_B  = (size_t)17 * 18 * 64 * 2;    // 39,168 (each of h,l)
constexpr size_t FEAT_B = (size_t)Bfull * 128 * 4;    // 262,144
constexpr size_t W1P_ELEMS = (size_t)7 * 4 * 16 * 32;        // 28672 ushort
constexpr size_t W2P_ELEMS = (size_t)25 * 2 * 64 * 32;       // 102400 ushort
constexpr size_t W3P_ELEMS = (size_t)9 * 2 * 2 * 128 * 32;   // 147456 ushort

__device__ __forceinline__ ushort_t f2bf_rne(float x) {
    unsigned u = __builtin_bit_cast(unsigned, x);
    unsigned r = (u + 0x7FFFu + ((u >> 16) & 1u)) >> 16;
    return (ushort_t)r;
}
__device__ __forceinline__ float bf2f(ushort_t b) {
    return __builtin_bit_cast(float, (unsigned)b << 16);
}

#define MFMA16(acc, a, b) \
    asm("v_mfma_f32_16x16x32_bf16 %0, %1, %2, %0" : "+v"(acc) : "v"(a), "v"(b))

// ---------------- rasterize -> padded bf16 [b][136r][136c][4ic] ----------------
__global__ __launch_bounds__(256) void rasterize_bf_k(const int* __restrict__ x,
                                                      ushort_t* __restrict__ tb, int b0) {
    int b_l = blockIdx.x;
    int rg  = blockIdx.y;             // row-group 0..7
    int b = b0 + b_l;
    __shared__ int pts[F][O][2];
    __shared__ int prm[F][24];
    int tid = threadIdx.x;
    if (tid < F * O * 2)
        ((int*)pts)[tid] = x[(size_t)b * F * O * 2 + tid];
    __syncthreads();
    if (tid < F) {
        int f = tid;
        int dX = 64 + pts[f][O - 1][0];
        int dY = 64 - pts[f][O - 1][1];
        prm[f][0] = dX; prm[f][1] = dY;
        prm[f][2] = dX >= 64 ? 64 : dX + 1; prm[f][3] = dX >= 64 ? dX - 1 : 64;
        prm[f][4] = dY >= 64 ? 64 : dY + 1; prm[f][5] = dY >= 64 ? dY - 1 : 64;
        for (int k = 0; k < O - 1; ++k) {
            prm[f][6 + k]  = (pts[f][k][0] + 64) % 127;
            prm[f][15 + k] = (64 - pts[f][k][1]) % 127;
        }
    }
    __syncthreads();
    ushort_t* outp = tb + (size_t)b_l * 136 * 136 * 4;
    int r0 = rg * 17;
    for (int i = tid; i < 17 * 136; i += 256) {
        int r = r0 + i / 136, c = i % 136;
        int y = r - 3, xx = c - 3;
        unsigned pack0 = 0, pack1 = 0;
        if (y >= 0 && y < 128 && xx >= 0 && xx < 128) {
            bool ctr9 = (y >= 63 && y <= 65 && xx >= 63 && xx <= 65);
            bool ctr1 = (y == 64 && xx == 64);
            #pragma unroll
            for (int f = 0; f < 4; ++f) {
                unsigned bf;
                if (ctr1) bf = 0x3F80u;
                else if (ctr9) bf = 0x3F00u;
                else {
                    int dX = prm[f][0];
                    bool mX = (xx >= prm[f][2]) && (xx <= prm[f][3]);
                    bool mY = (y >= prm[f][4]) && (y <= prm[f][5]);
                    bf = ((mX && y == 64) || (mY && xx == dX)) ? 0xBF80u : 0u;
                }
                if (f & 1) { if (f >> 1) pack1 |= bf << 16; else pack0 |= bf << 16; }
                else       { if (f >> 1) pack1 |= bf;       else pack0 |= bf; }
            }
        }
        uv2 pk; pk.x = pack0; pk.y = pack1;
        *(uv2*)(outp + ((size_t)r * 136 + c) * 4) = pk;
    }
    __syncthreads();
    if (tid < 4) {
        int f = tid;
        int r1 = r0 + 17;
        for (int k = 0; k < O - 1; ++k) {
            int a = prm[f][6 + k] + 3, bb = prm[f][15 + k] + 3;
            #pragma unroll
            for (int dy = -1; dy <= 1; ++dy) {
                int rr = bb + dy;
                if (rr >= r0 && rr < r1) {
                    ushort_t* rowp = outp + ((size_t)rr * 136 + a - 1) * 4 + f;
                    rowp[0] = 0x3F00u; rowp[4] = 0x3F00u; rowp[8] = 0x3F00u;
                }
            }
            if (bb >= r0 && bb < r1) outp[((size_t)bb * 136 + a) * 4 + f] = 0x3F80u;
        }
    }
}

// ---------------- prep_w1 ----------------
__global__ __launch_bounds__(256) void prep_w1_k(const float* __restrict__ w1,
                                                 ushort_t* __restrict__ w1p) {
    int idx = blockIdx.x * 256 + threadIdx.x;
    if (idx >= (int)W1P_ELEMS) return;
    int k = idx & 31, lr = (idx >> 5) & 15, slot = (idx >> 9) & 3, ky = idx >> 11;
    int hl = slot & 1, m = slot >> 1;
    int kx = k >> 2, ic = k & 3;
    int oc = m * 16 + lr;
    float w = (kx < 7) ? w1[((oc * 4 + ic) * 7 + ky) * 7 + kx] : 0.f;
    ushort_t h = f2bf_rne(w);
    w1p[idx] = hl ? f2bf_rne(w - bf2f(h)) : h;
}

// ---------------- conv1 + pool1 fused (1 pool row per wave, f32-LDS x-pool) ----------------
// grid (NB, 8); wave w owns pool row prow = yt*4+w (conv rows 2*prow..2*prow+2,
// rows never exceed 62). Row-pool in registers, [4][64][33] f32 LDS for x-pool.
__global__ __launch_bounds__(256) void conv1pool_k(const ushort_t* __restrict__ tb,
                                                   const ushort_t* __restrict__ w1p,
                                                   const float* __restrict__ b1,
                                                   ushort_t* __restrict__ p1h,
                                                   ushort_t* __restrict__ p1l) {
    __shared__ float sP[4 * 64 * 33];   // [wave][col][ch], +1 ch pad; 33,792 B
    int b_l = blockIdx.x;
    int yt  = blockIdx.y;               // 0..7
    int wave = threadIdx.x >> 6, lane = threadIdx.x & 63;
    int lr = lane & 15, lq = lane >> 4;
    int prow = yt * 4 + wave;           // 0..31 (31 skipped)
    const ushort_t* tbb = tb + (size_t)b_l * 136 * 136 * 4;
    int aoff = lr * 32 + lq * 8;
    float bias[2][4];
    #pragma unroll
    for (int m = 0; m < 2; ++m)
        #pragma unroll
        for (int j = 0; j < 4; ++j)
            bias[m][j] = b1[m * 16 + lq * 4 + j];

    f32x4 pacc[2][4];   // [m][xt]; relu >= 0 so 0 is max-identity
    #pragma unroll
    for (int m = 0; m < 2; ++m)
        #pragma unroll
        for (int xt = 0; xt < 4; ++xt)
            pacc[m][xt] = (f32x4)0.f;

    if (prow <= 30) {
        #pragma unroll 1
        for (int rr = 0; rr < 3; ++rr) {
            int oy = 2 * prow + rr;     // <= 62
            f32x4 acc[2][4];
            #pragma unroll
            for (int m = 0; m < 2; ++m)
                #pragma unroll
                for (int xt = 0; xt < 4; ++xt)
                    acc[m][xt] = (f32x4)0.f;
            #pragma unroll
            for (int ky = 0; ky < 7; ++ky) {
                const ushort_t* wb = w1p + (size_t)ky * 2048;
                uv4 ah0 = *(const uv4*)(wb + aoff);
                uv4 al0 = *(const uv4*)(wb + 512 + aoff);
                uv4 ah1 = *(const uv4*)(wb + 1024 + aoff);
                uv4 al1 = *(const uv4*)(wb + 1536 + aoff);
                const ushort_t* rb = tbb + (size_t)(2 * oy + ky) * (136 * 4);
                #pragma unroll
                for (int xt = 0; xt < 4; ++xt) {
                    uv4 bv = *(const uv4*)(rb + (size_t)(2 * (xt * 16 + lr) + 2 * lq) * 4);
                    MFMA16(acc[0][xt], ah0, bv);
                    MFMA16(acc[1][xt], ah1, bv);
                    MFMA16(acc[0][xt], al0, bv);
                    MFMA16(acc[1][xt], al1, bv);
                }
            }
            asm volatile("s_nop 7\n\ts_nop 7");
            #pragma unroll
            for (int m = 0; m < 2; ++m)
                #pragma unroll
                for (int xt = 0; xt < 4; ++xt)
                    #pragma unroll
                    for (int j = 0; j < 4; ++j) {
                        float v = fmaxf(acc[m][xt][j] + bias[m][j], 0.f);
                        pacc[m][xt][j] = fmaxf(pacc[m][xt][j], v);
                    }
        }
    }

    // write row-pooled values to LDS slot [wave]
    #pragma unroll
    for (int m = 0; m < 2; ++m)
        #pragma unroll
        for (int xt = 0; xt < 4; ++xt) {
            int col = xt * 16 + lr;
            float* dst = &sP[((size_t)wave * 64 + col) * 33 + m * 16 + lq * 4];
            #pragma unroll
            for (int j = 0; j < 4; ++j) dst[j] = pacc[m][xt][j];
        }
    __syncthreads();

    // x-pool + hi/lo split + store interior p1 cells
    for (int i = threadIdx.x; i < 4 * 31 * 32; i += 256) {
        int ch = i & 31; int t = i >> 5;
        int px = t % 31; int w = t / 31;
        int py = yt * 4 + w;
        if (py > 30) continue;
        const float* s = &sP[((size_t)w * 64 + 2 * px) * 33 + ch];
        float v = fmaxf(fmaxf(s[0], s[33]), s[66]);
        ushort_t h = f2bf_rne(v);
        size_t addr = (((size_t)b_l * 35 + py + 2) * 35 + px + 2) * 32 + ch;
        p1h[addr] = h;
        p1l[addr] = f2bf_rne(v - bf2f(h));
    }
}

// ---------------- prep_w2 ----------------
__global__ __launch_bounds__(256) void prep_w2_k(const float* __restrict__ w2,
                                                 ushort_t* __restrict__ w2p) {
    int idx = blockIdx.x * 256 + threadIdx.x;
    if (idx >= 25 * 64 * 32) return;
    int ic = idx & 31, oc = (idx >> 5) & 63, kk = idx >> 11;
    float w = w2[(size_t)(oc * 32 + ic) * 25 + kk];
    ushort_t h = f2bf_rne(w);
    w2p[(size_t)kk * 4096 + (idx & 2047)] = h;
    w2p[(size_t)kk * 4096 + 2048 + (idx & 2047)] = f2bf_rne(w - bf2f(h));
}

// ---------------- conv2 MFMA + LDS-staged B (pad-zeroing) + fused bias/relu/pool2 ----------------
__global__ __launch_bounds__(256) void conv2_mfma_k(const ushort_t* __restrict__ p1h,
                                                    const ushort_t* __restrict__ p1l,
                                                    const ushort_t* __restrict__ w2p,
                                                    const float* __restrict__ b2,
                                                    ushort_t* __restrict__ p2h,
                                                    ushort_t* __restrict__ p2l) {
    __shared__ ushort_t sB[2][13440];   // [plane][r<12][pc<35][k<32], swizzled k-chunk
    int b_l = blockIdx.x;
    int yt  = blockIdx.y;
    int y0 = yt * 8;
    int nrows = (35 - y0) < 12 ? (35 - y0) : 12;   // 12,12,12,11
    int tid = threadIdx.x;

    {
        int nchunks = nrows * 35 * 4;
        const ushort_t* src0 = p1h + (size_t)b_l * 35 * 1120 + (size_t)y0 * 1120;
        const ushort_t* src1 = p1l + (size_t)b_l * 35 * 1120 + (size_t)y0 * 1120;
        for (int c = tid; c < 2 * nchunks; c += 256) {
            int p = c >= nchunks;
            int cc = p ? c - nchunks : c;
            int lqi = cc & 3;
            int pc = (cc >> 2) % 35;
            int r = cc / 140;
            int pr_g = y0 + r;
            bool inb = (pr_g >= 2 && pr_g <= 32 && pc >= 2 && pc <= 32);
            const ushort_t* s = p ? src1 : src0;
            uv4 v = *(const uv4*)(s + (size_t)r * 1120 + pc * 32 + lqi * 8);
            if (!inb) v = (uv4)0u;     // p1 pads are never written: zero-fill here
            int swz = lqi ^ ((pc >> 1) & 3);
            *(uv4*)(&sB[p][(r * 35 + pc) * 32 + swz * 8]) = v;
        }
    }
    __syncthreads();

    int wave = threadIdx.x >> 6;
    int lane = threadIdx.x & 63;
    int wm = wave & 1, wy = wave >> 1;
    int oc0 = wm * 32;
    int lr = lane & 15, lq = lane >> 4;
    int rclip = 34 - y0;

    f32x4 acc[4][2][2];
    #pragma unroll
    for (int y = 0; y < 4; ++y)
        #pragma unroll
        for (int m = 0; m < 2; ++m)
            #pragma unroll
            for (int n = 0; n < 2; ++n)
                acc[y][m][n] = (f32x4)0.f;

    int aoff = (oc0 + lr) * 32 + lq * 8;

    #pragma unroll 1
    for (int kk = 0; kk < 25; ++kk) {
        int ky = kk / 5, kx = kk % 5;
        const ushort_t* wb = w2p + (size_t)kk * 4096;
        uv4 ah0 = *(const uv4*)(wb + aoff);
        uv4 ah1 = *(const uv4*)(wb + aoff + 512);
        uv4 al0 = *(const uv4*)(wb + 2048 + aoff);
        uv4 al1 = *(const uv4*)(wb + 2048 + aoff + 512);
        int pcc[2];
        #pragma unroll
        for (int xt = 0; xt < 2; ++xt) {
            int pc = xt * 16 + lr + kx; pc = pc > 34 ? 34 : pc;
            pcc[xt] = pc * 32 + (lq ^ ((pc >> 1) & 3)) * 8;
        }
        #pragma unroll
        for (int y = 0; y < 4; ++y) {
            int r = wy * 4 + y + ky; r = r > rclip ? rclip : r;
            int rbase = r * 1120;
            #pragma unroll
            for (int xt = 0; xt < 2; ++xt) {
                int off = rbase + pcc[xt];
                uv4 bh = *(const uv4*)(&sB[0][off]);
                uv4 bl = *(const uv4*)(&sB[1][off]);
                MFMA16(acc[y][0][xt], ah0, bh);
                MFMA16(acc[y][1][xt], ah1, bh);
                MFMA16(acc[y][0][xt], ah0, bl);
                MFMA16(acc[y][1][xt], ah1, bl);
                MFMA16(acc[y][0][xt], al0, bh);
                MFMA16(acc[y][1][xt], al1, bh);
            }
        }
    }
    asm volatile("s_nop 7\n\ts_nop 7");

    float bias[2][4];
    #pragma unroll
    for (int m = 0; m < 2; ++m)
        #pragma unroll
        for (int j = 0; j < 4; ++j)
            bias[m][j] = b2[oc0 + m * 16 + lq * 4 + j];

    int ybase = y0 + wy * 4;
    #pragma unroll
    for (int yp = 0; yp < 2; ++yp) {
        int yy = ybase + 2 * yp;
        if (yy + 1 > 30) continue;   // wave-uniform
        int py = yy >> 1;
        #pragma unroll
        for (int m = 0; m < 2; ++m)
            #pragma unroll
            for (int xt = 0; xt < 2; ++xt)
                #pragma unroll
                for (int j = 0; j < 4; ++j) {
                    float v = fmaxf(acc[2 * yp][m][xt][j], acc[2 * yp + 1][m][xt][j]);
                    float o = __shfl_xor(v, 1, 64);
                    v = fmaxf(fmaxf(v, o) + bias[m][j], 0.f);
                    int px = xt * 8 + (lr >> 1);
                    if (!(lane & 1) && px < 15) {
                        int oc = oc0 + m * 16 + lq * 4 + j;
                        size_t oo = (((size_t)b_l * 17 + py + 1) * 18 + px + 1) * 64 + oc;
                        ushort_t h = f2bf_rne(v);
                        p2h[oo] = h;
                        p2l[oo] = f2bf_rne(v - bf2f(h));
                    }
                }
    }
}

// ---------------- prep_w3 ----------------
__global__ __launch_bounds__(256) void prep_w3_k(const float* __restrict__ w3,
                                                 ushort_t* __restrict__ w3p) {
    int idx = blockIdx.x * 256 + threadIdx.x;
    if (idx >= (int)W3P_ELEMS) return;
    int kk = idx & 31, oc = (idx >> 5) & 127, hl = (idx >> 12) & 1, ks = (idx >> 13) & 1, kxy = idx >> 14;
    int ky = kxy / 3, kx = kxy % 3;
    int ic = ks * 32 + kk;
    float w = w3[((size_t)(oc * 64 + ic) * 3 + ky) * 3 + kx];
    ushort_t h = f2bf_rne(w);
    w3p[idx] = hl ? f2bf_rne(w - bf2f(h)) : h;
}

// ---------------- conv3 + pool3 + mean, fused -> feat ----------------
// p2 pads are never written in global: staging zero-fills pad cells.
__global__ __launch_bounds__(256) void conv3pool_k(const ushort_t* __restrict__ p2h,
                                                   const ushort_t* __restrict__ p2l,
                                                   const ushort_t* __restrict__ w3p,
                                                   const float* __restrict__ b3,
                                                   float* __restrict__ feat, int b0) {
    __shared__ ushort_t sB[2][19584];   // [plane][rc<306][64], 16B slots swizzled by c&7
    int b_l = blockIdx.x;
    int tid = threadIdx.x;
    {
        const ushort_t* s0 = p2h + (size_t)b_l * 19584;
        const ushort_t* s1 = p2l + (size_t)b_l * 19584;
        for (int ccg = tid; ccg < 4896; ccg += 256) {
            int p = ccg >= 2448;
            int cc = p ? ccg - 2448 : ccg;
            int rc = cc >> 3, slot = cc & 7;
            int r = rc / 18, c = rc % 18;
            bool pad = (r == 0 || r == 16 || c == 0 || c >= 16);
            uv4 v = *(const uv4*)((p ? s1 : s0) + (size_t)cc * 8);
            if (pad) v = (uv4)0u;
            *(uv4*)(&sB[p][rc * 64 + (slot ^ (c & 7)) * 8]) = v;
        }
    }
    __syncthreads();
    int wave = tid >> 6, lane = tid & 63;
    int lr = lane & 15, lq = lane >> 4;
    int oc0 = wave * 32;
    float bias[2][4];
    #pragma unroll
    for (int m = 0; m < 2; ++m)
        #pragma unroll
        for (int j = 0; j < 4; ++j)
            bias[m][j] = b3[oc0 + m * 16 + lq * 4 + j];
    f32x4 fsum[2];
    fsum[0] = (f32x4)0.f; fsum[1] = (f32x4)0.f;

    int cl = lr;
    #pragma unroll 1
    for (int pr = 0; pr < 7; ++pr) {
        f32x4 acc[2][2];
        #pragma unroll
        for (int rr = 0; rr < 2; ++rr) { acc[rr][0] = (f32x4)0.f; acc[rr][1] = (f32x4)0.f; }
        #pragma unroll 1
        for (int ky = 0; ky < 3; ++ky)
            #pragma unroll 1
            for (int kx = 0; kx < 3; ++kx) {
                int c = cl + kx;
                int cs = c & 7;
                #pragma unroll
                for (int ks = 0; ks < 2; ++ks) {
                    const ushort_t* wb = w3p + (size_t)(((ky * 3 + kx) * 2 + ks) * 2) * 4096;
                    uv4 ah0 = *(const uv4*)(wb + (oc0 + lr) * 32 + lq * 8);
                    uv4 ah1 = *(const uv4*)(wb + (oc0 + 16 + lr) * 32 + lq * 8);
                    uv4 al0 = *(const uv4*)(wb + 4096 + (oc0 + lr) * 32 + lq * 8);
                    uv4 al1 = *(const uv4*)(wb + 4096 + (oc0 + 16 + lr) * 32 + lq * 8);
                    int slotk = ((ks << 2) | lq) ^ cs;
                    #pragma unroll
                    for (int rr = 0; rr < 2; ++rr) {
                        int r = 2 * pr + rr + ky;
                        int off = (r * 18 + c) * 64 + slotk * 8;
                        uv4 bh = *(const uv4*)(&sB[0][off]);
                        uv4 bl = *(const uv4*)(&sB[1][off]);
                        MFMA16(acc[rr][0], ah0, bh);
                        MFMA16(acc[rr][1], ah1, bh);
                        MFMA16(acc[rr][0], ah0, bl);
                        MFMA16(acc[rr][1], ah1, bl);
                        MFMA16(acc[rr][0], al0, bh);
                        MFMA16(acc[rr][1], al1, bh);
                    }
                }
            }
        asm volatile("s_nop 7\n\ts_nop 7");
        #pragma unroll
        for (int m = 0; m < 2; ++m)
            #pragma unroll
            for (int j = 0; j < 4; ++j) {
                float v0 = fmaxf(acc[0][m][j] + bias[m][j], 0.f);
                float v1 = fmaxf(acc[1][m][j] + bias[m][j], 0.f);
                float vm = fmaxf(v0, v1);
                float o = __shfl_xor(vm, 1, 64);
                float pooled = fmaxf(vm, o);
                if (lr < 14) fsum[m][j] += pooled;
            }
    }
    #pragma unroll
    for (int m = 0; m < 2; ++m)
        #pragma unroll
        for (int j = 0; j < 4; ++j) {
            float t = fsum[m][j];
            t += __shfl_xor(t, 1, 64);
            t += __shfl_xor(t, 2, 64);
            t += __shfl_xor(t, 4, 64);
            t += __shfl_xor(t, 8, 64);
            if (lr == 0)
                feat[(size_t)(b0 + b_l) * 128 + oc0 + m * 16 + lq * 4 + j] = t * (1.f / 98.f);
        }
}

// ---------------- fc1 (relu) + fc2 ----------------
__global__ __launch_bounds__(128) void fc_k(const float* __restrict__ feat,
                                            const float* __restrict__ fw1,
                                            const float* __restrict__ fb1,
                                            const float* __restrict__ fw2,
                                            const float* __restrict__ fb2,
                                            float* __restrict__ out) {
    __shared__ float sF[128];
    __shared__ float sH[128];
    int b = blockIdx.x, tid = threadIdx.x;
    sF[tid] = feat[(size_t)b * 128 + tid];
    __syncthreads();
    const float4* wrow = (const float4*)(fw1 + (size_t)tid * 128);
    float s = fb1[tid];
    #pragma unroll
    for (int i = 0; i < 32; ++i) {
        float4 w = wrow[i];
        s = fmaf(w.x, sF[4 * i], s);
        s = fmaf(w.y, sF[4 * i + 1], s);
        s = fmaf(w.z, sF[4 * i + 2], s);
        s = fmaf(w.w, sF[4 * i + 3], s);
    }
    sH[tid] = fmaxf(s, 0.f);
    __syncthreads();
    if (tid < 5) {
        const float* w2r = fw2 + (size_t)tid * 128;
        float s2 = fb2[tid];
        for (int i = 0; i < 128; ++i) s2 = fmaf(w2r[i], sH[i], s2);
        out[(size_t)b * 5 + tid] = s2;
    }
}

// ---------------- launch ----------------
extern "C" void kernel_launch(void* const* d_in, const int* in_sizes, int n_in,
                              void* d_out, int out_size, void* d_ws, size_t ws_size,
                              hipStream_t stream) {
    const int*   x   = (const int*)d_in[0];
    const float* w1  = (const float*)d_in[1];
    const float* b1  = (const float*)d_in[2];
    const float* w2  = (const float*)d_in[3];
    const float* b2  = (const float*)d_in[4];
    const float* w3  = (const float*)d_in[5];
    const float* b3  = (const float*)d_in[6];
    const float* fw1 = (const float*)d_in[7];
    const float* fb1 = (const float*)d_in[8];
    const float* fw2 = (const float*)d_in[9];
    const float* fb2 = (const float*)d_in[10];
    float* out = (float*)d_out;

    const size_t per_img = TB_B + 2 * P1_B + 2 * P2_B;   // 383,104 B
    const size_t fixed_b = FEAT_B + (W1P_ELEMS + W2P_ELEMS + W3P_ELEMS) * 2 + 1024;
    int NB = Bfull;
    while (NB > 128 && fixed_b + per_img * (size_t)NB > ws_size) NB >>= 1;

    char* base = (char*)d_ws;
    float* feat = (float*)base;                         base += FEAT_B;
    ushort_t* tb  = (ushort_t*)base;                    base += (size_t)NB * TB_B;
    ushort_t* p1h = (ushort_t*)base;                    base += (size_t)NB * P1_B;
    ushort_t* p1l = (ushort_t*)base;                    base += (size_t)NB * P1_B;
    ushort_t* p2h = (ushort_t*)base;                    base += (size_t)NB * P2_B;
    ushort_t* p2l = (ushort_t*)base;                    base += (size_t)NB * P2_B;
    ushort_t* w1p = (ushort_t*)base;                    base += W1P_ELEMS * 2;
    ushort_t* w2p = (ushort_t*)base;                    base += W2P_ELEMS * 2;
    ushort_t* w3p = (ushort_t*)base;

    prep_w1_k<<<((int)W1P_ELEMS + 255) / 256, 256, 0, stream>>>(w1, w1p);
    prep_w2_k<<<(25 * 64 * 32 + 255) / 256, 256, 0, stream>>>(w2, w2p);
    prep_w3_k<<<((int)W3P_ELEMS + 255) / 256, 256, 0, stream>>>(w3, w3p);

    const int nchunk = Bfull / NB;
    for (int ch = 0; ch < nchunk; ++ch) {
        int b0 = ch * NB;
        rasterize_bf_k<<<dim3(NB, 8), 256, 0, stream>>>(x, tb, b0);
        conv1pool_k<<<dim3(NB, 8), 256, 0, stream>>>(tb, w1p, b1, p1h, p1l);
        conv2_mfma_k<<<dim3(NB, 4), 256, 0, stream>>>(p1h, p1l, w2p, b2, p2h, p2l);
        conv3pool_k<<<NB, 256, 0, stream>>>(p2h, p2l, w3p, b3, feat, b0);
    }
    fc_k<<<Bfull, 128, 0, stream>>>(feat, fw1, fb1, fw2, fb2, out);
}